// Round 1
// baseline (684.956 us; speedup 1.0000x reference)
//
#include <hip/hip_runtime.h>
#include <hip/hip_bf16.h>

#define HIDDEN 1024
#define NHEADS 16
#define HEADD  64
#define BATCH  4
#define SEQ    2048
#define MROWS  (BATCH*SEQ)
#define LN_EPS 1e-5f
#define QK_SCALE 0.03125f   // 1024^-0.5

using bf16 = __hip_bfloat16;
typedef short bf16x8 __attribute__((ext_vector_type(8)));
typedef float f32x4 __attribute__((ext_vector_type(4)));

#define MFMA16(a,b,c) __builtin_amdgcn_mfma_f32_16x16x32_bf16((a),(b),(c),0,0,0)

__device__ __forceinline__ void gload_lds16(const void* g, void* l) {
  __builtin_amdgcn_global_load_lds(
      (const __attribute__((address_space(1))) void*)g,
      (__attribute__((address_space(3))) void*)l, 16, 0, 0);
}

__device__ __forceinline__ unsigned short f2bf_bits(float f) {
  bf16 b = __float2bfloat16(f);
  return __builtin_bit_cast(unsigned short, b);
}

// ---------------- LayerNorm + bf16 cast ----------------
__global__ __launch_bounds__(256) void ln_cast_kernel(
    const float* __restrict__ x, const float* __restrict__ gamma,
    const float* __restrict__ beta, bf16* __restrict__ h) {
  const int row = blockIdx.x;
  const int t = threadIdx.x;
  const float* xr = x + (size_t)row * HIDDEN;
  float4 v = reinterpret_cast<const float4*>(xr)[t];
  float s  = v.x + v.y + v.z + v.w;
  float s2 = v.x*v.x + v.y*v.y + v.z*v.z + v.w*v.w;
  #pragma unroll
  for (int off = 32; off >= 1; off >>= 1) {
    s  += __shfl_xor(s, off);
    s2 += __shfl_xor(s2, off);
  }
  __shared__ float red[8];
  const int wv = t >> 6;
  if ((t & 63) == 0) { red[wv] = s; red[4 + wv] = s2; }
  __syncthreads();
  s  = red[0] + red[1] + red[2] + red[3];
  s2 = red[4] + red[5] + red[6] + red[7];
  const float mu   = s * (1.0f / HIDDEN);
  const float var  = s2 * (1.0f / HIDDEN) - mu * mu;
  const float rstd = rsqrtf(var + LN_EPS);
  float4 g4 = reinterpret_cast<const float4*>(gamma)[t];
  float4 b4 = reinterpret_cast<const float4*>(beta)[t];
  ushort4 pk;
  pk.x = f2bf_bits((v.x - mu) * rstd * g4.x + b4.x);
  pk.y = f2bf_bits((v.y - mu) * rstd * g4.y + b4.y);
  pk.z = f2bf_bits((v.z - mu) * rstd * g4.z + b4.z);
  pk.w = f2bf_bits((v.w - mu) * rstd * g4.w + b4.w);
  reinterpret_cast<ushort4*>(h + (size_t)row * HIDDEN)[t] = pk;
}

// ---------------- Weight transpose fp32 -> bf16 (W^T) ----------------
__global__ __launch_bounds__(256) void wtrans_kernel(
    const float* __restrict__ Wq, const float* __restrict__ Wk,
    const float* __restrict__ Wv, const float* __restrict__ Wo,
    bf16* __restrict__ WTqkv, bf16* __restrict__ WoT) {
  __shared__ float tile[32][33];
  const int mat = blockIdx.z;
  const float* W = (mat == 0) ? Wq : (mat == 1) ? Wk : (mat == 2) ? Wv : Wo;
  bf16* WT = (mat < 3) ? (WTqkv + (size_t)mat * HIDDEN * HIDDEN) : WoT;
  const int tx = threadIdx.x & 31, ty = threadIdx.x >> 5;  // 32 x 8
  const int n0 = blockIdx.x * 32, k0 = blockIdx.y * 32;
  #pragma unroll
  for (int i = 0; i < 32; i += 8)
    tile[ty + i][tx] = W[(size_t)(k0 + ty + i) * HIDDEN + n0 + tx];
  __syncthreads();
  #pragma unroll
  for (int i = 0; i < 32; i += 8)
    WT[(size_t)(n0 + ty + i) * HIDDEN + k0 + tx] = __float2bfloat16(tile[tx][ty + i]);
}

// ---------------- GEMM: C[M,N] = A[M,K] * Bt[N,K]^T  (m97-style) ----------------
// EPI 0: QKV epilogue (scatter to Q/K/V [B,H,L,D], bias, SCALE on Q)
// EPI 1: float out + bias + residual
template <int EPI>
__global__ __launch_bounds__(256) void gemm_kernel(
    const bf16* __restrict__ A, const bf16* __restrict__ Bt, int Ksz,
    const float* __restrict__ bias0, const float* __restrict__ bias1,
    const float* __restrict__ bias2, const float* __restrict__ resid,
    bf16* __restrict__ q_out, bf16* __restrict__ k_out, bf16* __restrict__ v_out,
    float* __restrict__ f_out) {
  __shared__ bf16 As[128 * 32];
  __shared__ bf16 Bs[128 * 32];
  const int t = threadIdx.x;
  const int wave = t >> 6, lane = t & 63;
  const int wr = wave >> 1, wc = wave & 1;
  const int m0 = blockIdx.y * 128, n0 = blockIdx.x * 128;
  const int lr = lane & 15, lk = (lane >> 4) * 8;
  const f32x4 zero = {0.f, 0.f, 0.f, 0.f};
  f32x4 acc[4][4];
  #pragma unroll
  for (int i = 0; i < 4; ++i)
    #pragma unroll
    for (int j = 0; j < 4; ++j) acc[i][j] = zero;

  const int ar = t >> 2;          // 0..63
  const int ac = (t & 3) * 8;     // 0,8,16,24
  const bf16* Ag = A + (size_t)(m0 + ar) * Ksz + ac;
  const bf16* Bg = Bt + (size_t)(n0 + ar) * Ksz + ac;

  for (int k0 = 0; k0 < Ksz; k0 += 32) {
    if (k0) __syncthreads();
    gload_lds16(Ag + k0,                     &As[t * 8]);
    gload_lds16(Ag + (size_t)64 * Ksz + k0,  &As[2048 + t * 8]);
    gload_lds16(Bg + k0,                     &Bs[t * 8]);
    gload_lds16(Bg + (size_t)64 * Ksz + k0,  &Bs[2048 + t * 8]);
    __syncthreads();
    bf16x8 af[4], bfr[4];
    #pragma unroll
    for (int i = 0; i < 4; ++i)
      af[i] = *reinterpret_cast<const bf16x8*>(&As[(wr * 64 + i * 16 + lr) * 32 + lk]);
    #pragma unroll
    for (int i = 0; i < 4; ++i)
      bfr[i] = *reinterpret_cast<const bf16x8*>(&Bs[(wc * 64 + i * 16 + lr) * 32 + lk]);
    #pragma unroll
    for (int i = 0; i < 4; ++i)
      #pragma unroll
      for (int j = 0; j < 4; ++j)
        acc[i][j] = MFMA16(af[i], bfr[j], acc[i][j]);
  }

  const int rb = (lane >> 4) * 4;
  if (EPI == 0) {
    #pragma unroll
    for (int nf = 0; nf < 4; ++nf) {
      const int cg = n0 + wc * 64 + nf * 16 + lr;
      const int which = cg >> 10;           // 0=q 1=k 2=v (uniform per frag)
      const int hid = cg & 1023;
      const int head = hid >> 6, d = hid & 63;
      const float bias = (which == 0 ? bias0 : which == 1 ? bias1 : bias2)[hid];
      #pragma unroll
      for (int mf = 0; mf < 4; ++mf) {
        #pragma unroll
        for (int j = 0; j < 4; ++j) {
          const int rg = m0 + wr * 64 + mf * 16 + rb + j;
          const int b_ = rg >> 11, l_ = rg & 2047;
          const float val = acc[mf][nf][j] + bias;
          const size_t off = ((size_t)(b_ * NHEADS + head) * SEQ + l_) * HEADD + d;
          if (which == 2)       v_out[off] = __float2bfloat16(val);
          else if (which == 1)  k_out[off] = __float2bfloat16(val);
          else                  q_out[off] = __float2bfloat16(val * QK_SCALE);
        }
      }
    }
  } else {
    #pragma unroll
    for (int nf = 0; nf < 4; ++nf) {
      const int cg = n0 + wc * 64 + nf * 16 + lr;
      const float bias = bias0[cg];
      #pragma unroll
      for (int mf = 0; mf < 4; ++mf) {
        #pragma unroll
        for (int j = 0; j < 4; ++j) {
          const int rg = m0 + wr * 64 + mf * 16 + rb + j;
          const size_t off = (size_t)rg * HIDDEN + cg;
          f_out[off] = acc[mf][nf][j] + bias + resid[off];
        }
      }
    }
  }
}

// ---------------- V transpose [B,H,L,D] -> [B,H,D,L] ----------------
__global__ __launch_bounds__(256) void vtrans_kernel(
    const unsigned short* __restrict__ V, unsigned short* __restrict__ Vt) {
  __shared__ unsigned short tile[64][72];
  const int bh = blockIdx.y;
  const int l0 = blockIdx.x * 64;
  const int t = threadIdx.x;
  const unsigned short* Vs = V + ((size_t)bh * SEQ + l0) * HEADD;
  #pragma unroll
  for (int p = 0; p < 4; ++p) {
    const int idx = p * 256 + t;
    const int r = idx >> 4;          // l offset 0..63
    const int c = (idx & 15) * 4;    // d offset
    ushort4 v4 = *reinterpret_cast<const ushort4*>(&Vs[r * HEADD + c]);
    tile[r][c] = v4.x; tile[r][c + 1] = v4.y; tile[r][c + 2] = v4.z; tile[r][c + 3] = v4.w;
  }
  __syncthreads();
  unsigned short* Vd = Vt + (size_t)bh * HEADD * SEQ + l0;
  #pragma unroll
  for (int p = 0; p < 4; ++p) {
    const int idx = p * 256 + t;
    const int d = idx >> 4;          // d row 0..63
    const int c = (idx & 15) * 4;    // l offset
    ushort4 o4 = make_ushort4(tile[c][d], tile[c + 1][d], tile[c + 2][d], tile[c + 3][d]);
    *reinterpret_cast<ushort4*>(&Vd[(size_t)d * SEQ + c]) = o4;
  }
}

// ---------------- Causal flash attention ----------------
// grid: (L/64, B*NH), 256 threads = 4 independent waves, each owns 16 q-rows.
__global__ __launch_bounds__(256) void attn_kernel(
    const bf16* __restrict__ Q, const bf16* __restrict__ K,
    const bf16* __restrict__ Vt, bf16* __restrict__ O) {
  __shared__ bf16 P_lds[4][16][64];
  const int wave = threadIdx.x >> 6, lane = threadIdx.x & 63;
  const int bh = blockIdx.y;
  const int q0 = blockIdx.x * 64 + wave * 16;
  const int lr = lane & 15, lk = (lane >> 4) * 8;
  const bf16* Qh = Q + (size_t)bh * SEQ * HEADD;
  const bf16* Kh = K + (size_t)bh * SEQ * HEADD;
  const bf16* Vh = Vt + (size_t)bh * HEADD * SEQ;
  const bf16x8 qf0 = *reinterpret_cast<const bf16x8*>(&Qh[(size_t)(q0 + lr) * HEADD + lk]);
  const bf16x8 qf1 = *reinterpret_cast<const bf16x8*>(&Qh[(size_t)(q0 + lr) * HEADD + 32 + lk]);
  const f32x4 zero = {0.f, 0.f, 0.f, 0.f};
  f32x4 o[4];
  #pragma unroll
  for (int n = 0; n < 4; ++n) o[n] = zero;
  float mrow[4] = {-1e30f, -1e30f, -1e30f, -1e30f};
  float lrow[4] = {0.f, 0.f, 0.f, 0.f};
  const int rq = q0 + (lane >> 4) * 4;   // rows rq..rq+3 live in this lane

  for (int kv0 = 0; kv0 < q0 + 16; kv0 += 64) {
    // S = Q K^T  (16q x 64kv in 4 frags)
    f32x4 s[4];
    #pragma unroll
    for (int n = 0; n < 4; ++n) {
      const bf16x8 kf0 = *reinterpret_cast<const bf16x8*>(&Kh[(size_t)(kv0 + n * 16 + lr) * HEADD + lk]);
      const bf16x8 kf1 = *reinterpret_cast<const bf16x8*>(&Kh[(size_t)(kv0 + n * 16 + lr) * HEADD + 32 + lk]);
      s[n] = MFMA16(qf0, kf0, zero);
      s[n] = MFMA16(qf1, kf1, s[n]);
    }
    // causal mask + tile rowmax
    float tmax[4] = {-1e30f, -1e30f, -1e30f, -1e30f};
    #pragma unroll
    for (int n = 0; n < 4; ++n) {
      const int kvg = kv0 + n * 16 + lr;
      #pragma unroll
      for (int j = 0; j < 4; ++j) {
        if (kvg > rq + j) s[n][j] = -1e30f;
        tmax[j] = fmaxf(tmax[j], s[n][j]);
      }
    }
    #pragma unroll
    for (int off = 1; off < 16; off <<= 1)
      #pragma unroll
      for (int j = 0; j < 4; ++j)
        tmax[j] = fmaxf(tmax[j], __shfl_xor(tmax[j], off));
    // online softmax update
    float alpha[4];
    #pragma unroll
    for (int j = 0; j < 4; ++j) {
      const float mn = fmaxf(mrow[j], tmax[j]);
      alpha[j] = __expf(mrow[j] - mn);
      mrow[j] = mn;
    }
    float rsum[4] = {0.f, 0.f, 0.f, 0.f};
    #pragma unroll
    for (int n = 0; n < 4; ++n)
      #pragma unroll
      for (int j = 0; j < 4; ++j) {
        const float p = __expf(s[n][j] - mrow[j]);
        s[n][j] = p;
        rsum[j] += p;
      }
    #pragma unroll
    for (int off = 1; off < 16; off <<= 1)
      #pragma unroll
      for (int j = 0; j < 4; ++j)
        rsum[j] += __shfl_xor(rsum[j], off);
    #pragma unroll
    for (int j = 0; j < 4; ++j)
      lrow[j] = lrow[j] * alpha[j] + rsum[j];
    #pragma unroll
    for (int n = 0; n < 4; ++n)
      #pragma unroll
      for (int j = 0; j < 4; ++j)
        o[n][j] *= alpha[j];
    // P -> LDS (acc layout -> A-frag layout), per-wave private region
    #pragma unroll
    for (int n = 0; n < 4; ++n)
      #pragma unroll
      for (int j = 0; j < 4; ++j)
        P_lds[wave][(lane >> 4) * 4 + j][n * 16 + lr] = __float2bfloat16(s[n][j]);
    asm volatile("s_waitcnt lgkmcnt(0)" ::: "memory");  // cross-lane LDS visibility (same wave)
    __builtin_amdgcn_sched_barrier(0);
    // O += P * V  (Vt gives 8-contiguous kv per lane)
    #pragma unroll
    for (int ks = 0; ks < 2; ++ks) {
      const bf16x8 pa = *reinterpret_cast<const bf16x8*>(&P_lds[wave][lr][ks * 32 + lk]);
      #pragma unroll
      for (int n = 0; n < 4; ++n) {
        const bf16x8 vf = *reinterpret_cast<const bf16x8*>(
            &Vh[(size_t)(n * 16 + lr) * SEQ + kv0 + ks * 32 + lk]);
        o[n] = MFMA16(pa, vf, o[n]);
      }
    }
    __builtin_amdgcn_sched_barrier(0);
    asm volatile("" ::: "memory");  // keep next iter's P writes after this iter's reads
  }

  const int b_ = bh >> 4, h_ = bh & 15;
  float inv[4];
  #pragma unroll
  for (int j = 0; j < 4; ++j) inv[j] = 1.0f / lrow[j];
  #pragma unroll
  for (int n = 0; n < 4; ++n)
    #pragma unroll
    for (int j = 0; j < 4; ++j)
      O[((size_t)(b_ * SEQ + rq + j)) * HIDDEN + h_ * HEADD + n * 16 + lr] =
          __float2bfloat16(o[n][j] * inv[j]);
}

// ---------------- launch ----------------
extern "C" void kernel_launch(void* const* d_in, const int* in_sizes, int n_in,
                              void* d_out, int out_size, void* d_ws, size_t ws_size,
                              hipStream_t stream) {
  const float* x     = (const float*)d_in[0];
  // d_in[1] = mask (causal tril, hard-coded in attn kernel)
  const float* Wq    = (const float*)d_in[2];
  const float* bq    = (const float*)d_in[3];
  const float* Wk    = (const float*)d_in[4];
  const float* bk    = (const float*)d_in[5];
  const float* Wv    = (const float*)d_in[6];
  const float* bv    = (const float*)d_in[7];
  const float* Wo    = (const float*)d_in[8];
  const float* bo    = (const float*)d_in[9];
  const float* gamma = (const float*)d_in[10];
  const float* beta  = (const float*)d_in[11];

  char* ws = (char*)d_ws;
  const size_t MB = (size_t)1 << 20;
  bf16* h     = (bf16*)(ws + 0 * MB);    // 16 MB (reused as O after QKV GEMM)
  bf16* Qb    = (bf16*)(ws + 16 * MB);   // 16 MB  [B,H,L,D]
  bf16* Kb    = (bf16*)(ws + 32 * MB);   // 16 MB  [B,H,L,D]
  bf16* Vtmp  = (bf16*)(ws + 48 * MB);   // 16 MB  [B,H,L,D]
  bf16* Vt    = (bf16*)(ws + 64 * MB);   // 16 MB  [B,H,D,L]
  bf16* WTqkv = (bf16*)(ws + 80 * MB);   // 6 MB   [3072,1024]
  bf16* WoT   = (bf16*)(ws + 86 * MB);   // 2 MB   [1024,1024]
  bf16* Ob    = h;                       // reuse: h dead after QKV GEMM

  ln_cast_kernel<<<MROWS, 256, 0, stream>>>(x, gamma, beta, h);
  wtrans_kernel<<<dim3(32, 32, 4), 256, 0, stream>>>(Wq, Wk, Wv, Wo, WTqkv, WoT);
  gemm_kernel<0><<<dim3(24, 64), 256, 0, stream>>>(
      h, WTqkv, HIDDEN, bq, bk, bv, nullptr, Qb, Kb, Vtmp, nullptr);
  vtrans_kernel<<<dim3(SEQ / 64, BATCH * NHEADS), 256, 0, stream>>>(
      (const unsigned short*)Vtmp, (unsigned short*)Vt);
  attn_kernel<<<dim3(SEQ / 64, BATCH * NHEADS), 256, 0, stream>>>(Qb, Kb, Vt, Ob);
  gemm_kernel<1><<<dim3(8, 64), 256, 0, stream>>>(
      Ob, WoT, HIDDEN, bo, nullptr, nullptr, x, nullptr, nullptr, nullptr, (float*)d_out);
}

// Round 2
// 679.015 us; speedup vs baseline: 1.0087x; 1.0087x over previous
//
#include <hip/hip_runtime.h>
#include <hip/hip_bf16.h>

#define HIDDEN 1024
#define NHEADS 16
#define HEADD  64
#define BATCH  4
#define SEQ    2048
#define MROWS  (BATCH*SEQ)
#define LN_EPS 1e-5f
#define QK_SCALE 0.03125f   // 1024^-0.5

using bf16 = __hip_bfloat16;
typedef short bf16x8 __attribute__((ext_vector_type(8)));
typedef float f32x4 __attribute__((ext_vector_type(4)));

#define MFMA16(a,b,c) __builtin_amdgcn_mfma_f32_16x16x32_bf16((a),(b),(c),0,0,0)

__device__ __forceinline__ void gload_lds16(const void* g, void* l) {
  __builtin_amdgcn_global_load_lds(
      (const __attribute__((address_space(1))) void*)g,
      (__attribute__((address_space(3))) void*)l, 16, 0, 0);
}

__device__ __forceinline__ unsigned short f2bf_bits(float f) {
  bf16 b = __float2bfloat16(f);
  return __builtin_bit_cast(unsigned short, b);
}

// ---------------- LayerNorm + bf16 cast ----------------
__global__ __launch_bounds__(256) void ln_cast_kernel(
    const float* __restrict__ x, const float* __restrict__ gamma,
    const float* __restrict__ beta, bf16* __restrict__ h) {
  const int row = blockIdx.x;
  const int t = threadIdx.x;
  const float* xr = x + (size_t)row * HIDDEN;
  float4 v = reinterpret_cast<const float4*>(xr)[t];
  float s  = v.x + v.y + v.z + v.w;
  float s2 = v.x*v.x + v.y*v.y + v.z*v.z + v.w*v.w;
  #pragma unroll
  for (int off = 32; off >= 1; off >>= 1) {
    s  += __shfl_xor(s, off);
    s2 += __shfl_xor(s2, off);
  }
  __shared__ float red[8];
  const int wv = t >> 6;
  if ((t & 63) == 0) { red[wv] = s; red[4 + wv] = s2; }
  __syncthreads();
  s  = red[0] + red[1] + red[2] + red[3];
  s2 = red[4] + red[5] + red[6] + red[7];
  const float mu   = s * (1.0f / HIDDEN);
  const float var  = s2 * (1.0f / HIDDEN) - mu * mu;
  const float rstd = rsqrtf(var + LN_EPS);
  float4 g4 = reinterpret_cast<const float4*>(gamma)[t];
  float4 b4 = reinterpret_cast<const float4*>(beta)[t];
  ushort4 pk;
  pk.x = f2bf_bits((v.x - mu) * rstd * g4.x + b4.x);
  pk.y = f2bf_bits((v.y - mu) * rstd * g4.y + b4.y);
  pk.z = f2bf_bits((v.z - mu) * rstd * g4.z + b4.z);
  pk.w = f2bf_bits((v.w - mu) * rstd * g4.w + b4.w);
  reinterpret_cast<ushort4*>(h + (size_t)row * HIDDEN)[t] = pk;
}

// ---------------- Weight transpose fp32 -> bf16 (W^T) ----------------
__global__ __launch_bounds__(256) void wtrans_kernel(
    const float* __restrict__ Wq, const float* __restrict__ Wk,
    const float* __restrict__ Wv, const float* __restrict__ Wo,
    bf16* __restrict__ WTqkv, bf16* __restrict__ WoT) {
  __shared__ float tile[32][33];
  const int mat = blockIdx.z;
  const float* W = (mat == 0) ? Wq : (mat == 1) ? Wk : (mat == 2) ? Wv : Wo;
  bf16* WT = (mat < 3) ? (WTqkv + (size_t)mat * HIDDEN * HIDDEN) : WoT;
  const int tx = threadIdx.x & 31, ty = threadIdx.x >> 5;  // 32 x 8
  const int n0 = blockIdx.x * 32, k0 = blockIdx.y * 32;
  #pragma unroll
  for (int i = 0; i < 32; i += 8)
    tile[ty + i][tx] = W[(size_t)(k0 + ty + i) * HIDDEN + n0 + tx];
  __syncthreads();
  #pragma unroll
  for (int i = 0; i < 32; i += 8)
    WT[(size_t)(n0 + ty + i) * HIDDEN + k0 + tx] = __float2bfloat16(tile[tx][ty + i]);
}

// ---------------- GEMM: C[M,N] = A[M,K] * Bt[N,K]^T  (m97-style) ----------------
template <int EPI>
__global__ __launch_bounds__(256) void gemm_kernel(
    const bf16* __restrict__ A, const bf16* __restrict__ Bt, int Ksz,
    const float* __restrict__ bias0, const float* __restrict__ bias1,
    const float* __restrict__ bias2, const float* __restrict__ resid,
    bf16* __restrict__ q_out, bf16* __restrict__ k_out, bf16* __restrict__ v_out,
    float* __restrict__ f_out) {
  __shared__ bf16 As[128 * 32];
  __shared__ bf16 Bs[128 * 32];
  const int t = threadIdx.x;
  const int wave = t >> 6, lane = t & 63;
  const int wr = wave >> 1, wc = wave & 1;
  const int m0 = blockIdx.y * 128, n0 = blockIdx.x * 128;
  const int lr = lane & 15, lk = (lane >> 4) * 8;
  const f32x4 zero = {0.f, 0.f, 0.f, 0.f};
  f32x4 acc[4][4];
  #pragma unroll
  for (int i = 0; i < 4; ++i)
    #pragma unroll
    for (int j = 0; j < 4; ++j) acc[i][j] = zero;

  const int ar = t >> 2;          // 0..63
  const int ac = (t & 3) * 8;     // 0,8,16,24
  const bf16* Ag = A + (size_t)(m0 + ar) * Ksz + ac;
  const bf16* Bg = Bt + (size_t)(n0 + ar) * Ksz + ac;

  for (int k0 = 0; k0 < Ksz; k0 += 32) {
    if (k0) __syncthreads();
    gload_lds16(Ag + k0,                     &As[t * 8]);
    gload_lds16(Ag + (size_t)64 * Ksz + k0,  &As[2048 + t * 8]);
    gload_lds16(Bg + k0,                     &Bs[t * 8]);
    gload_lds16(Bg + (size_t)64 * Ksz + k0,  &Bs[2048 + t * 8]);
    __syncthreads();
    bf16x8 af[4], bfr[4];
    #pragma unroll
    for (int i = 0; i < 4; ++i)
      af[i] = *reinterpret_cast<const bf16x8*>(&As[(wr * 64 + i * 16 + lr) * 32 + lk]);
    #pragma unroll
    for (int i = 0; i < 4; ++i)
      bfr[i] = *reinterpret_cast<const bf16x8*>(&Bs[(wc * 64 + i * 16 + lr) * 32 + lk]);
    #pragma unroll
    for (int i = 0; i < 4; ++i)
      #pragma unroll
      for (int j = 0; j < 4; ++j)
        acc[i][j] = MFMA16(af[i], bfr[j], acc[i][j]);
  }

  const int rb = (lane >> 4) * 4;
  if (EPI == 0) {
    #pragma unroll
    for (int nf = 0; nf < 4; ++nf) {
      const int cg = n0 + wc * 64 + nf * 16 + lr;
      const int which = cg >> 10;           // 0=q 1=k 2=v (uniform per frag)
      const int hid = cg & 1023;
      const int head = hid >> 6, d = hid & 63;
      const float bias = (which == 0 ? bias0 : which == 1 ? bias1 : bias2)[hid];
      #pragma unroll
      for (int mf = 0; mf < 4; ++mf) {
        #pragma unroll
        for (int j = 0; j < 4; ++j) {
          const int rg = m0 + wr * 64 + mf * 16 + rb + j;
          const int b_ = rg >> 11, l_ = rg & 2047;
          const float val = acc[mf][nf][j] + bias;
          const size_t off = ((size_t)(b_ * NHEADS + head) * SEQ + l_) * HEADD + d;
          if (which == 2)       v_out[off] = __float2bfloat16(val);
          else if (which == 1)  k_out[off] = __float2bfloat16(val);
          else                  q_out[off] = __float2bfloat16(val * QK_SCALE);
        }
      }
    }
  } else {
    #pragma unroll
    for (int nf = 0; nf < 4; ++nf) {
      const int cg = n0 + wc * 64 + nf * 16 + lr;
      const float bias = bias0[cg];
      #pragma unroll
      for (int mf = 0; mf < 4; ++mf) {
        #pragma unroll
        for (int j = 0; j < 4; ++j) {
          const int rg = m0 + wr * 64 + mf * 16 + rb + j;
          const size_t off = (size_t)rg * HIDDEN + cg;
          f_out[off] = acc[mf][nf][j] + bias + resid[off];
        }
      }
    }
  }
}

// ---------------- V transpose [B,H,L,D] -> [B,H,D,L] ----------------
__global__ __launch_bounds__(256) void vtrans_kernel(
    const unsigned short* __restrict__ V, unsigned short* __restrict__ Vt) {
  __shared__ unsigned short tile[64][72];
  const int bh = blockIdx.y;
  const int l0 = blockIdx.x * 64;
  const int t = threadIdx.x;
  const unsigned short* Vs = V + ((size_t)bh * SEQ + l0) * HEADD;
  #pragma unroll
  for (int p = 0; p < 4; ++p) {
    const int idx = p * 256 + t;
    const int r = idx >> 4;
    const int c = (idx & 15) * 4;
    ushort4 v4 = *reinterpret_cast<const ushort4*>(&Vs[r * HEADD + c]);
    tile[r][c] = v4.x; tile[r][c + 1] = v4.y; tile[r][c + 2] = v4.z; tile[r][c + 3] = v4.w;
  }
  __syncthreads();
  unsigned short* Vd = Vt + (size_t)bh * HEADD * SEQ + l0;
  #pragma unroll
  for (int p = 0; p < 4; ++p) {
    const int idx = p * 256 + t;
    const int d = idx >> 4;
    const int c = (idx & 15) * 4;
    ushort4 o4 = make_ushort4(tile[c][d], tile[c + 1][d], tile[c + 2][d], tile[c + 3][d]);
    *reinterpret_cast<ushort4*>(&Vd[(size_t)d * SEQ + c]) = o4;
  }
}

// ---------------- Causal flash attention (v2) ----------------
// grid: (L/64, B*NH), 256 threads = 4 waves, each wave owns 16 q-rows.
// LPT: strip = 31 - blockIdx.x so longest blocks dispatch first.
// Per tile: prefetch all K+V frags to regs, softmax hides V latency.
#define PSTRIDE 72   // bf16 elems per P_lds row: 144 B, 16B-aligned, de-conflicted

__device__ __forceinline__ void attn_strip(
    const bf16* __restrict__ Qh, const bf16* __restrict__ Kh,
    const bf16* __restrict__ Vh, bf16* __restrict__ O,
    int bh, int q0, int lane, bf16* __restrict__ Prow) {
  const int lr = lane & 15, g = lane >> 4, lk = g * 8;
  const bf16x8 qf0 = *reinterpret_cast<const bf16x8*>(&Qh[(size_t)(q0 + lr) * HEADD + lk]);
  const bf16x8 qf1 = *reinterpret_cast<const bf16x8*>(&Qh[(size_t)(q0 + lr) * HEADD + 32 + lk]);
  const f32x4 zero = {0.f, 0.f, 0.f, 0.f};
  f32x4 o[4];
  #pragma unroll
  for (int n = 0; n < 4; ++n) o[n] = zero;
  float mrow[4] = {-1e30f, -1e30f, -1e30f, -1e30f};
  float lrow[4] = {0.f, 0.f, 0.f, 0.f};
  const int rq = q0 + g * 4;
  const int ntiles = (q0 >> 6) + 1;

  for (int t = 0; t < ntiles; ++t) {
    const int kv0 = t * 64;
    // prefetch K and V fragments for this tile (16 independent 16B loads)
    bf16x8 kf0[4], kf1[4], vf0[4], vf1[4];
    #pragma unroll
    for (int n = 0; n < 4; ++n) {
      const bf16* kp = &Kh[(size_t)(kv0 + n * 16 + lr) * HEADD + lk];
      kf0[n] = *reinterpret_cast<const bf16x8*>(kp);
      kf1[n] = *reinterpret_cast<const bf16x8*>(kp + 32);
    }
    #pragma unroll
    for (int n = 0; n < 4; ++n) {
      const bf16* vp = &Vh[(size_t)(n * 16 + lr) * SEQ + kv0 + lk];
      vf0[n] = *reinterpret_cast<const bf16x8*>(vp);
      vf1[n] = *reinterpret_cast<const bf16x8*>(vp + 32);
    }
    // S = Q K^T
    f32x4 s[4];
    __builtin_amdgcn_s_setprio(1);
    #pragma unroll
    for (int n = 0; n < 4; ++n) {
      s[n] = MFMA16(qf0, kf0[n], zero);
      s[n] = MFMA16(qf1, kf1[n], s[n]);
    }
    __builtin_amdgcn_s_setprio(0);
    // causal mask only on the diagonal (last) tile
    if (t == ntiles - 1) {
      #pragma unroll
      for (int n = 0; n < 4; ++n) {
        const int kvg = kv0 + n * 16 + lr;
        #pragma unroll
        for (int j = 0; j < 4; ++j)
          if (kvg > rq + j) s[n][j] = -1e30f;
      }
    }
    // tile rowmax
    float tmax[4] = {-1e30f, -1e30f, -1e30f, -1e30f};
    #pragma unroll
    for (int n = 0; n < 4; ++n)
      #pragma unroll
      for (int j = 0; j < 4; ++j)
        tmax[j] = fmaxf(tmax[j], s[n][j]);
    #pragma unroll
    for (int off = 1; off < 16; off <<= 1)
      #pragma unroll
      for (int j = 0; j < 4; ++j)
        tmax[j] = fmaxf(tmax[j], __shfl_xor(tmax[j], off));
    float alpha[4];
    #pragma unroll
    for (int j = 0; j < 4; ++j) {
      const float mn = fmaxf(mrow[j], tmax[j]);
      alpha[j] = __expf(mrow[j] - mn);
      mrow[j] = mn;
    }
    float rsum[4] = {0.f, 0.f, 0.f, 0.f};
    #pragma unroll
    for (int n = 0; n < 4; ++n)
      #pragma unroll
      for (int j = 0; j < 4; ++j) {
        const float p = __expf(s[n][j] - mrow[j]);
        s[n][j] = p;
        rsum[j] += p;
      }
    #pragma unroll
    for (int off = 1; off < 16; off <<= 1)
      #pragma unroll
      for (int j = 0; j < 4; ++j)
        rsum[j] += __shfl_xor(rsum[j], off);
    #pragma unroll
    for (int j = 0; j < 4; ++j)
      lrow[j] = lrow[j] * alpha[j] + rsum[j];
    #pragma unroll
    for (int n = 0; n < 4; ++n)
      #pragma unroll
      for (int j = 0; j < 4; ++j)
        o[n][j] *= alpha[j];
    // P -> LDS (layout convert to A-frag), wave-private region
    #pragma unroll
    for (int n = 0; n < 4; ++n)
      #pragma unroll
      for (int j = 0; j < 4; ++j)
        Prow[(g * 4 + j) * PSTRIDE + n * 16 + lr] = __float2bfloat16(s[n][j]);
    asm volatile("s_waitcnt lgkmcnt(0)" ::: "memory");
    __builtin_amdgcn_sched_barrier(0);
    // O += P * V  (V frags already in registers)
    __builtin_amdgcn_s_setprio(1);
    #pragma unroll
    for (int ks = 0; ks < 2; ++ks) {
      const bf16x8 pa = *reinterpret_cast<const bf16x8*>(&Prow[lr * PSTRIDE + ks * 32 + lk]);
      #pragma unroll
      for (int n = 0; n < 4; ++n)
        o[n] = MFMA16(pa, ks ? vf1[n] : vf0[n], o[n]);
    }
    __builtin_amdgcn_s_setprio(0);
  }

  const int b_ = bh >> 4, h_ = bh & 15;
  float inv[4];
  #pragma unroll
  for (int j = 0; j < 4; ++j) inv[j] = 1.0f / lrow[j];
  #pragma unroll
  for (int n = 0; n < 4; ++n)
    #pragma unroll
    for (int j = 0; j < 4; ++j)
      O[((size_t)(b_ * SEQ + rq + j)) * HIDDEN + h_ * HEADD + n * 16 + lr] =
          __float2bfloat16(o[n][j] * inv[j]);
}

__global__ __launch_bounds__(256, 4) void attn_kernel(
    const bf16* __restrict__ Q, const bf16* __restrict__ K,
    const bf16* __restrict__ Vt, bf16* __restrict__ O) {
  __shared__ bf16 P_lds[4][16 * PSTRIDE];
  const int wave = threadIdx.x >> 6, lane = threadIdx.x & 63;
  const int bh = blockIdx.y;
  const int strip = 31 - blockIdx.x;            // LPT: long blocks first
  const int q0 = strip * 64 + wave * 16;
  const bf16* Qh = Q + (size_t)bh * SEQ * HEADD;
  const bf16* Kh = K + (size_t)bh * SEQ * HEADD;
  const bf16* Vh = Vt + (size_t)bh * HEADD * SEQ;
  attn_strip(Qh, Kh, Vh, O, bh, q0, lane, &P_lds[wave][0]);
}

// ---------------- launch ----------------
extern "C" void kernel_launch(void* const* d_in, const int* in_sizes, int n_in,
                              void* d_out, int out_size, void* d_ws, size_t ws_size,
                              hipStream_t stream) {
  const float* x     = (const float*)d_in[0];
  const float* Wq    = (const float*)d_in[2];
  const float* bq    = (const float*)d_in[3];
  const float* Wk    = (const float*)d_in[4];
  const float* bk    = (const float*)d_in[5];
  const float* Wv    = (const float*)d_in[6];
  const float* bv    = (const float*)d_in[7];
  const float* Wo    = (const float*)d_in[8];
  const float* bo    = (const float*)d_in[9];
  const float* gamma = (const float*)d_in[10];
  const float* beta  = (const float*)d_in[11];

  char* ws = (char*)d_ws;
  const size_t MB = (size_t)1 << 20;
  bf16* h     = (bf16*)(ws + 0 * MB);
  bf16* Qb    = (bf16*)(ws + 16 * MB);
  bf16* Kb    = (bf16*)(ws + 32 * MB);
  bf16* Vtmp  = (bf16*)(ws + 48 * MB);
  bf16* Vt    = (bf16*)(ws + 64 * MB);
  bf16* WTqkv = (bf16*)(ws + 80 * MB);
  bf16* WoT   = (bf16*)(ws + 86 * MB);
  bf16* Ob    = h;

  ln_cast_kernel<<<MROWS, 256, 0, stream>>>(x, gamma, beta, h);
  wtrans_kernel<<<dim3(32, 32, 4), 256, 0, stream>>>(Wq, Wk, Wv, Wo, WTqkv, WoT);
  gemm_kernel<0><<<dim3(24, 64), 256, 0, stream>>>(
      h, WTqkv, HIDDEN, bq, bk, bv, nullptr, Qb, Kb, Vtmp, nullptr);
  vtrans_kernel<<<dim3(SEQ / 64, BATCH * NHEADS), 256, 0, stream>>>(
      (const unsigned short*)Vtmp, (unsigned short*)Vt);
  attn_kernel<<<dim3(SEQ / 64, BATCH * NHEADS), 256, 0, stream>>>(Qb, Kb, Vt, Ob);
  gemm_kernel<1><<<dim3(8, 64), 256, 0, stream>>>(
      Ob, WoT, HIDDEN, bo, nullptr, nullptr, x, nullptr, nullptr, nullptr, (float*)d_out);
}

// Round 3
// 545.082 us; speedup vs baseline: 1.2566x; 1.2457x over previous
//
#include <hip/hip_runtime.h>
#include <hip/hip_bf16.h>

#define HIDDEN 1024
#define NHEADS 16
#define HEADD  64
#define BATCH  4
#define SEQ    2048
#define MROWS  (BATCH*SEQ)
#define LN_EPS 1e-5f
#define QK_SCALE 0.03125f   // 1024^-0.5

using bf16 = __hip_bfloat16;
typedef short bf16x8 __attribute__((ext_vector_type(8)));
typedef float f32x4 __attribute__((ext_vector_type(4)));
typedef float f32x16 __attribute__((ext_vector_type(16)));

#define MFMA16(a,b,c) __builtin_amdgcn_mfma_f32_16x16x32_bf16((a),(b),(c),0,0,0)
#define MFMA32(a,b,c) __builtin_amdgcn_mfma_f32_32x32x16_bf16((a),(b),(c),0,0,0)

__device__ __forceinline__ void gload_lds16(const void* g, void* l) {
  __builtin_amdgcn_global_load_lds(
      (const __attribute__((address_space(1))) void*)g,
      (__attribute__((address_space(3))) void*)l, 16, 0, 0);
}

__device__ __forceinline__ unsigned short f2bf_bits(float f) {
  bf16 b = __float2bfloat16(f);
  return __builtin_bit_cast(unsigned short, b);
}

__device__ __forceinline__ unsigned long long pack4bf(float a, float b, float c, float d) {
  return (unsigned long long)f2bf_bits(a)
       | ((unsigned long long)f2bf_bits(b) << 16)
       | ((unsigned long long)f2bf_bits(c) << 32)
       | ((unsigned long long)f2bf_bits(d) << 48);
}

// ---------------- LayerNorm + bf16 cast ----------------
__global__ __launch_bounds__(256) void ln_cast_kernel(
    const float* __restrict__ x, const float* __restrict__ gamma,
    const float* __restrict__ beta, bf16* __restrict__ h) {
  const int row = blockIdx.x;
  const int t = threadIdx.x;
  const float* xr = x + (size_t)row * HIDDEN;
  float4 v = reinterpret_cast<const float4*>(xr)[t];
  float s  = v.x + v.y + v.z + v.w;
  float s2 = v.x*v.x + v.y*v.y + v.z*v.z + v.w*v.w;
  #pragma unroll
  for (int off = 32; off >= 1; off >>= 1) {
    s  += __shfl_xor(s, off);
    s2 += __shfl_xor(s2, off);
  }
  __shared__ float red[8];
  const int wv = t >> 6;
  if ((t & 63) == 0) { red[wv] = s; red[4 + wv] = s2; }
  __syncthreads();
  s  = red[0] + red[1] + red[2] + red[3];
  s2 = red[4] + red[5] + red[6] + red[7];
  const float mu   = s * (1.0f / HIDDEN);
  const float var  = s2 * (1.0f / HIDDEN) - mu * mu;
  const float rstd = rsqrtf(var + LN_EPS);
  float4 g4 = reinterpret_cast<const float4*>(gamma)[t];
  float4 b4 = reinterpret_cast<const float4*>(beta)[t];
  ushort4 pk;
  pk.x = f2bf_bits((v.x - mu) * rstd * g4.x + b4.x);
  pk.y = f2bf_bits((v.y - mu) * rstd * g4.y + b4.y);
  pk.z = f2bf_bits((v.z - mu) * rstd * g4.z + b4.z);
  pk.w = f2bf_bits((v.w - mu) * rstd * g4.w + b4.w);
  reinterpret_cast<ushort4*>(h + (size_t)row * HIDDEN)[t] = pk;
}

// ---------------- Weight transpose fp32 -> bf16 (W^T) ----------------
__global__ __launch_bounds__(256) void wtrans_kernel(
    const float* __restrict__ Wq, const float* __restrict__ Wk,
    const float* __restrict__ Wv, const float* __restrict__ Wo,
    bf16* __restrict__ WTqkv, bf16* __restrict__ WoT) {
  __shared__ float tile[32][33];
  const int mat = blockIdx.z;
  const float* W = (mat == 0) ? Wq : (mat == 1) ? Wk : (mat == 2) ? Wv : Wo;
  bf16* WT = (mat < 3) ? (WTqkv + (size_t)mat * HIDDEN * HIDDEN) : WoT;
  const int tx = threadIdx.x & 31, ty = threadIdx.x >> 5;
  const int n0 = blockIdx.x * 32, k0 = blockIdx.y * 32;
  #pragma unroll
  for (int i = 0; i < 32; i += 8)
    tile[ty + i][tx] = W[(size_t)(k0 + ty + i) * HIDDEN + n0 + tx];
  __syncthreads();
  #pragma unroll
  for (int i = 0; i < 32; i += 8)
    WT[(size_t)(n0 + ty + i) * HIDDEN + k0 + tx] = __float2bfloat16(tile[tx][ty + i]);
}

// ---------------- GEMM: C[M,N] = A[M,K] * Bt[N,K]^T  (m97-style) ----------------
template <int EPI>
__global__ __launch_bounds__(256) void gemm_kernel(
    const bf16* __restrict__ A, const bf16* __restrict__ Bt, int Ksz,
    const float* __restrict__ bias0, const float* __restrict__ bias1,
    const float* __restrict__ bias2, const float* __restrict__ resid,
    bf16* __restrict__ q_out, bf16* __restrict__ k_out, bf16* __restrict__ v_out,
    float* __restrict__ f_out) {
  __shared__ bf16 As[128 * 32];
  __shared__ bf16 Bs[128 * 32];
  const int t = threadIdx.x;
  const int wave = t >> 6, lane = t & 63;
  const int wr = wave >> 1, wc = wave & 1;
  const int m0 = blockIdx.y * 128, n0 = blockIdx.x * 128;
  const int lr = lane & 15, lk = (lane >> 4) * 8;
  const f32x4 zero = {0.f, 0.f, 0.f, 0.f};
  f32x4 acc[4][4];
  #pragma unroll
  for (int i = 0; i < 4; ++i)
    #pragma unroll
    for (int j = 0; j < 4; ++j) acc[i][j] = zero;

  const int ar = t >> 2;
  const int ac = (t & 3) * 8;
  const bf16* Ag = A + (size_t)(m0 + ar) * Ksz + ac;
  const bf16* Bg = Bt + (size_t)(n0 + ar) * Ksz + ac;

  for (int k0 = 0; k0 < Ksz; k0 += 32) {
    if (k0) __syncthreads();
    gload_lds16(Ag + k0,                     &As[t * 8]);
    gload_lds16(Ag + (size_t)64 * Ksz + k0,  &As[2048 + t * 8]);
    gload_lds16(Bg + k0,                     &Bs[t * 8]);
    gload_lds16(Bg + (size_t)64 * Ksz + k0,  &Bs[2048 + t * 8]);
    __syncthreads();
    bf16x8 af[4], bfr[4];
    #pragma unroll
    for (int i = 0; i < 4; ++i)
      af[i] = *reinterpret_cast<const bf16x8*>(&As[(wr * 64 + i * 16 + lr) * 32 + lk]);
    #pragma unroll
    for (int i = 0; i < 4; ++i)
      bfr[i] = *reinterpret_cast<const bf16x8*>(&Bs[(wc * 64 + i * 16 + lr) * 32 + lk]);
    #pragma unroll
    for (int i = 0; i < 4; ++i)
      #pragma unroll
      for (int j = 0; j < 4; ++j)
        acc[i][j] = MFMA16(af[i], bfr[j], acc[i][j]);
  }

  const int rb = (lane >> 4) * 4;
  if (EPI == 0) {
    #pragma unroll
    for (int nf = 0; nf < 4; ++nf) {
      const int cg = n0 + wc * 64 + nf * 16 + lr;
      const int which = cg >> 10;
      const int hid = cg & 1023;
      const int head = hid >> 6, d = hid & 63;
      const float bias = (which == 0 ? bias0 : which == 1 ? bias1 : bias2)[hid];
      #pragma unroll
      for (int mf = 0; mf < 4; ++mf) {
        #pragma unroll
        for (int j = 0; j < 4; ++j) {
          const int rg = m0 + wr * 64 + mf * 16 + rb + j;
          const int b_ = rg >> 11, l_ = rg & 2047;
          const float val = acc[mf][nf][j] + bias;
          const size_t off = ((size_t)(b_ * NHEADS + head) * SEQ + l_) * HEADD + d;
          if (which == 2)       v_out[off] = __float2bfloat16(val);
          else if (which == 1)  k_out[off] = __float2bfloat16(val);
          else                  q_out[off] = __float2bfloat16(val * QK_SCALE);
        }
      }
    }
  } else {
    #pragma unroll
    for (int nf = 0; nf < 4; ++nf) {
      const int cg = n0 + wc * 64 + nf * 16 + lr;
      const float bias = bias0[cg];
      #pragma unroll
      for (int mf = 0; mf < 4; ++mf) {
        #pragma unroll
        for (int j = 0; j < 4; ++j) {
          const int rg = m0 + wr * 64 + mf * 16 + rb + j;
          const size_t off = (size_t)rg * HIDDEN + cg;
          f_out[off] = acc[mf][nf][j] + bias + resid[off];
        }
      }
    }
  }
}

// ---------------- V transpose [B,H,L,D] -> [B,H,D,L] ----------------
__global__ __launch_bounds__(256) void vtrans_kernel(
    const unsigned short* __restrict__ V, unsigned short* __restrict__ Vt) {
  __shared__ unsigned short tile[64][72];
  const int bh = blockIdx.y;
  const int l0 = blockIdx.x * 64;
  const int t = threadIdx.x;
  const unsigned short* Vs = V + ((size_t)bh * SEQ + l0) * HEADD;
  #pragma unroll
  for (int p = 0; p < 4; ++p) {
    const int idx = p * 256 + t;
    const int r = idx >> 4;
    const int c = (idx & 15) * 4;
    ushort4 v4 = *reinterpret_cast<const ushort4*>(&Vs[r * HEADD + c]);
    tile[r][c] = v4.x; tile[r][c + 1] = v4.y; tile[r][c + 2] = v4.z; tile[r][c + 3] = v4.w;
  }
  __syncthreads();
  unsigned short* Vd = Vt + (size_t)bh * HEADD * SEQ + l0;
  #pragma unroll
  for (int p = 0; p < 4; ++p) {
    const int idx = p * 256 + t;
    const int d = idx >> 4;
    const int c = (idx & 15) * 4;
    ushort4 o4 = make_ushort4(tile[c][d], tile[c + 1][d], tile[c + 2][d], tile[c + 3][d]);
    *reinterpret_cast<ushort4*>(&Vd[(size_t)d * SEQ + c]) = o4;
  }
}

// ---------------- Causal flash attention (v3: 32x32 swapped QK^T) ----------------
// 256 thr = 4 waves; each wave owns 32 q-rows. Swapped QK^T: S^T = K·Q^T so
// col = q = lane&31 (each lane holds 32 of its q-row's 64 kv scores; partner
// lane (^32) holds the complement). In-lane softmax with defer-max (THR=8).
// P round-trips through warp-private LDS with 8B-granule XOR swizzle.
// C/D 32x32 map: col=lane&31, row=(reg&3)+8*(reg>>2)+4*(lane>>5).
__global__ __launch_bounds__(256, 3) void attn_kernel(
    const bf16* __restrict__ Q, const bf16* __restrict__ K,
    const bf16* __restrict__ Vt, bf16* __restrict__ O) {
  __shared__ unsigned long long Plds[4][32 * 16];   // per-warp 4 KB: 32 q x 64 kv bf16
  const int wave = threadIdx.x >> 6, lane = threadIdx.x & 63;
  const int ql = lane & 31, hi = lane >> 5;
  const int bh = blockIdx.y;
  const int strip = 15 - (int)blockIdx.x;           // LPT: long strips first
  const int q0 = strip * 128 + wave * 32;
  const bf16* Qh = Q + (size_t)bh * SEQ * HEADD;
  const bf16* Kh = K + (size_t)bh * SEQ * HEADD;
  const bf16* Vh = Vt + (size_t)bh * HEADD * SEQ;
  unsigned long long* Pw = &Plds[wave][0];

  // Q as B-operand: lane holds Q[q=ql][k-slice kk*16 + hi*8 .. +8]
  const bf16* Qr = &Qh[(size_t)(q0 + ql) * HEADD + hi * 8];
  const bf16x8 qf0 = *reinterpret_cast<const bf16x8*>(Qr);
  const bf16x8 qf1 = *reinterpret_cast<const bf16x8*>(Qr + 16);
  const bf16x8 qf2 = *reinterpret_cast<const bf16x8*>(Qr + 32);
  const bf16x8 qf3 = *reinterpret_cast<const bf16x8*>(Qr + 48);

  const f32x16 z16 = {0.f,0.f,0.f,0.f,0.f,0.f,0.f,0.f,0.f,0.f,0.f,0.f,0.f,0.f,0.f,0.f};
  f32x16 o0 = z16, o1 = z16;
  float mrun = 0.f, lsum = 0.f;
  const int rq = q0 + ql;
  const int ntiles = (q0 >> 6) + 1;
  const int swz = ql & 15;

  for (int t = 0; t < ntiles; ++t) {
    const int kv0 = t * 64;
    // --- QK^T (swapped): A = K rows (kv), B = Q cols (q) ---
    const bf16* K0 = &Kh[(size_t)(kv0 + ql) * HEADD + hi * 8];
    const bf16* K1 = &Kh[(size_t)(kv0 + 32 + ql) * HEADD + hi * 8];
    f32x16 s0 = z16, s1 = z16;
    bf16x8 kf;
    __builtin_amdgcn_s_setprio(1);
    kf = *reinterpret_cast<const bf16x8*>(K0);       s0 = MFMA32(kf, qf0, s0);
    kf = *reinterpret_cast<const bf16x8*>(K0 + 16);  s0 = MFMA32(kf, qf1, s0);
    kf = *reinterpret_cast<const bf16x8*>(K0 + 32);  s0 = MFMA32(kf, qf2, s0);
    kf = *reinterpret_cast<const bf16x8*>(K0 + 48);  s0 = MFMA32(kf, qf3, s0);
    kf = *reinterpret_cast<const bf16x8*>(K1);       s1 = MFMA32(kf, qf0, s1);
    kf = *reinterpret_cast<const bf16x8*>(K1 + 16);  s1 = MFMA32(kf, qf1, s1);
    kf = *reinterpret_cast<const bf16x8*>(K1 + 32);  s1 = MFMA32(kf, qf2, s1);
    kf = *reinterpret_cast<const bf16x8*>(K1 + 48);  s1 = MFMA32(kf, qf3, s1);
    __builtin_amdgcn_s_setprio(0);
    // --- causal mask (diagonal tile only) ---
    if (t == ntiles - 1) {
      #pragma unroll
      for (int r = 0; r < 16; ++r) {
        const int kvg = kv0 + (r & 3) + 8 * (r >> 2) + 4 * hi;
        if (kvg > rq)      s0[r] = -1e30f;
        if (kvg + 32 > rq) s1[r] = -1e30f;
      }
    }
    // --- in-lane rowmax tree (own 32 of 64 kv) ---
    float tm[16];
    #pragma unroll
    for (int r = 0; r < 16; ++r) tm[r] = fmaxf(s0[r], s1[r]);
    #pragma unroll
    for (int st = 8; st >= 1; st >>= 1)
      #pragma unroll
      for (int r = 0; r < st; ++r) tm[r] = fmaxf(tm[r], tm[r + st]);
    const float pmax = tm[0];
    // --- defer-max: rescale only if any row grew past THR=8 (rare) ---
    if (!__all(pmax - mrun <= 8.f)) {
      const float fullmax = fmaxf(pmax, __shfl_xor(pmax, 32));
      const float mnew = fmaxf(mrun, fullmax);
      const float al = __expf(mrun - mnew);
      float* Pa = (float*)Pw;
      Pa[ql] = al;                       // both halves write identical value
      asm volatile("s_waitcnt lgkmcnt(0)" ::: "memory");
      __builtin_amdgcn_sched_barrier(0);
      #pragma unroll
      for (int r = 0; r < 16; ++r) {
        const float ar = Pa[(r & 3) + 8 * (r >> 2) + 4 * hi];
        o0[r] *= ar; o1[r] *= ar;
      }
      lsum *= al;
      mrun = mnew;
      __builtin_amdgcn_sched_barrier(0);
    }
    // --- exp + rowsum (in-lane) ---
    #pragma unroll
    for (int r = 0; r < 16; ++r) {
      s0[r] = __expf(s0[r] - mrun);
      s1[r] = __expf(s1[r] - mrun);
    }
    #pragma unroll
    for (int r = 0; r < 16; ++r) tm[r] = s0[r] + s1[r];
    #pragma unroll
    for (int st = 8; st >= 1; st >>= 1)
      #pragma unroll
      for (int r = 0; r < st; ++r) tm[r] += tm[r + st];
    lsum += tm[0];
    // --- pack P -> LDS (b64 writes, XOR-swizzled 8B granules) ---
    // write i covers kv = 8*(i&3) + 4*hi + 32*(i>>2) + {0..3} of row ql
    #pragma unroll
    for (int i = 0; i < 8; ++i) {
      const int g = 2 * (i & 3) + hi + 8 * (i >> 2);
      unsigned long long w;
      if (i < 4) w = pack4bf(s0[4*i],     s0[4*i+1],     s0[4*i+2],     s0[4*i+3]);
      else       w = pack4bf(s1[4*(i-4)], s1[4*(i-4)+1], s1[4*(i-4)+2], s1[4*(i-4)+3]);
      Pw[ql * 16 + (g ^ swz)] = w;
    }
    asm volatile("s_waitcnt lgkmcnt(0)" ::: "memory");
    __builtin_amdgcn_sched_barrier(0);
    // --- PV: A = P[q][kv-slice], B = Vt[d][kv] ---
    __builtin_amdgcn_s_setprio(1);
    #pragma unroll
    for (int ks = 0; ks < 4; ++ks) {
      const int ga = (4 * ks + 2 * hi) ^ swz;
      const int gb = (4 * ks + 2 * hi + 1) ^ swz;
      union { unsigned long long u[2]; bf16x8 v; } uu;
      uu.u[0] = Pw[ql * 16 + ga];
      uu.u[1] = Pw[ql * 16 + gb];
      const bf16* Vp = &Vh[(size_t)ql * SEQ + kv0 + ks * 16 + hi * 8];
      const bf16x8 v0 = *reinterpret_cast<const bf16x8*>(Vp);
      const bf16x8 v1 = *reinterpret_cast<const bf16x8*>(Vp + 32 * SEQ);
      o0 = MFMA32(uu.v, v0, o0);
      o1 = MFMA32(uu.v, v1, o1);
    }
    __builtin_amdgcn_s_setprio(0);
    __builtin_amdgcn_sched_barrier(0);
  }

  // --- epilogue: combine halves' rowsums, normalize, store ---
  const float ltot = lsum + __shfl_xor(lsum, 32);
  float* Pb = (float*)Pw;
  Pb[ql] = 1.0f / ltot;                 // both halves write identical value
  asm volatile("s_waitcnt lgkmcnt(0)" ::: "memory");
  __builtin_amdgcn_sched_barrier(0);
  const int b_ = bh >> 4, h_ = bh & 15;
  #pragma unroll
  for (int r = 0; r < 16; ++r) {
    const int row = (r & 3) + 8 * (r >> 2) + 4 * hi;
    const float iv = Pb[row];
    bf16* dst = &O[((size_t)(b_ * SEQ + q0 + row)) * HIDDEN + h_ * HEADD + ql];
    dst[0]  = __float2bfloat16(o0[r] * iv);
    dst[32] = __float2bfloat16(o1[r] * iv);
  }
}

// ---------------- launch ----------------
extern "C" void kernel_launch(void* const* d_in, const int* in_sizes, int n_in,
                              void* d_out, int out_size, void* d_ws, size_t ws_size,
                              hipStream_t stream) {
  const float* x     = (const float*)d_in[0];
  const float* Wq    = (const float*)d_in[2];
  const float* bq    = (const float*)d_in[3];
  const float* Wk    = (const float*)d_in[4];
  const float* bk    = (const float*)d_in[5];
  const float* Wv    = (const float*)d_in[6];
  const float* bv    = (const float*)d_in[7];
  const float* Wo    = (const float*)d_in[8];
  const float* bo    = (const float*)d_in[9];
  const float* gamma = (const float*)d_in[10];
  const float* beta  = (const float*)d_in[11];

  char* ws = (char*)d_ws;
  const size_t MB = (size_t)1 << 20;
  bf16* h     = (bf16*)(ws + 0 * MB);
  bf16* Qb    = (bf16*)(ws + 16 * MB);
  bf16* Kb    = (bf16*)(ws + 32 * MB);
  bf16* Vtmp  = (bf16*)(ws + 48 * MB);
  bf16* Vt    = (bf16*)(ws + 64 * MB);
  bf16* WTqkv = (bf16*)(ws + 80 * MB);
  bf16* WoT   = (bf16*)(ws + 86 * MB);
  bf16* Ob    = h;

  ln_cast_kernel<<<MROWS, 256, 0, stream>>>(x, gamma, beta, h);
  wtrans_kernel<<<dim3(32, 32, 4), 256, 0, stream>>>(Wq, Wk, Wv, Wo, WTqkv, WoT);
  gemm_kernel<0><<<dim3(24, 64), 256, 0, stream>>>(
      h, WTqkv, HIDDEN, bq, bk, bv, nullptr, Qb, Kb, Vtmp, nullptr);
  vtrans_kernel<<<dim3(SEQ / 64, BATCH * NHEADS), 256, 0, stream>>>(
      (const unsigned short*)Vtmp, (unsigned short*)Vt);
  attn_kernel<<<dim3(16, BATCH * NHEADS), 256, 0, stream>>>(Qb, Kb, Vt, Ob);
  gemm_kernel<1><<<dim3(8, 64), 256, 0, stream>>>(
      Ob, WoT, HIDDEN, bo, nullptr, nullptr, x, nullptr, nullptr, nullptr, (float*)d_out);
}

// Round 4
// 352.381 us; speedup vs baseline: 1.9438x; 1.5469x over previous
//
#include <hip/hip_runtime.h>
#include <hip/hip_bf16.h>

#define HIDDEN 1024
#define NHEADS 16
#define HEADD  64
#define BATCH  4
#define SEQ    2048
#define MROWS  (BATCH*SEQ)
#define LN_EPS 1e-5f
#define QK_SCALE 0.03125f   // 1024^-0.5

using bf16 = __hip_bfloat16;
typedef short bf16x8 __attribute__((ext_vector_type(8)));
typedef float f32x4 __attribute__((ext_vector_type(4)));
typedef float f32x16 __attribute__((ext_vector_type(16)));

#define MFMA16(a,b,c) __builtin_amdgcn_mfma_f32_16x16x32_bf16((a),(b),(c),0,0,0)
#define MFMA32(a,b,c) __builtin_amdgcn_mfma_f32_32x32x16_bf16((a),(b),(c),0,0,0)

__device__ __forceinline__ void gload_lds16(const void* g, void* l) {
  __builtin_amdgcn_global_load_lds(
      (const __attribute__((address_space(1))) void*)g,
      (__attribute__((address_space(3))) void*)l, 16, 0, 0);
}

__device__ __forceinline__ unsigned short f2bf_bits(float f) {
  bf16 b = __float2bfloat16(f);
  return __builtin_bit_cast(unsigned short, b);
}

__device__ __forceinline__ unsigned long long pack4bf(float a, float b, float c, float d) {
  return (unsigned long long)f2bf_bits(a)
       | ((unsigned long long)f2bf_bits(b) << 16)
       | ((unsigned long long)f2bf_bits(c) << 32)
       | ((unsigned long long)f2bf_bits(d) << 48);
}

// ---------------- LayerNorm + bf16 cast ----------------
__global__ __launch_bounds__(256) void ln_cast_kernel(
    const float* __restrict__ x, const float* __restrict__ gamma,
    const float* __restrict__ beta, bf16* __restrict__ h) {
  const int row = blockIdx.x;
  const int t = threadIdx.x;
  const float* xr = x + (size_t)row * HIDDEN;
  float4 v = reinterpret_cast<const float4*>(xr)[t];
  float s  = v.x + v.y + v.z + v.w;
  float s2 = v.x*v.x + v.y*v.y + v.z*v.z + v.w*v.w;
  #pragma unroll
  for (int off = 32; off >= 1; off >>= 1) {
    s  += __shfl_xor(s, off);
    s2 += __shfl_xor(s2, off);
  }
  __shared__ float red[8];
  const int wv = t >> 6;
  if ((t & 63) == 0) { red[wv] = s; red[4 + wv] = s2; }
  __syncthreads();
  s  = red[0] + red[1] + red[2] + red[3];
  s2 = red[4] + red[5] + red[6] + red[7];
  const float mu   = s * (1.0f / HIDDEN);
  const float var  = s2 * (1.0f / HIDDEN) - mu * mu;
  const float rstd = rsqrtf(var + LN_EPS);
  float4 g4 = reinterpret_cast<const float4*>(gamma)[t];
  float4 b4 = reinterpret_cast<const float4*>(beta)[t];
  ushort4 pk;
  pk.x = f2bf_bits((v.x - mu) * rstd * g4.x + b4.x);
  pk.y = f2bf_bits((v.y - mu) * rstd * g4.y + b4.y);
  pk.z = f2bf_bits((v.z - mu) * rstd * g4.z + b4.z);
  pk.w = f2bf_bits((v.w - mu) * rstd * g4.w + b4.w);
  reinterpret_cast<ushort4*>(h + (size_t)row * HIDDEN)[t] = pk;
}

// ---------------- Weight transpose fp32 -> bf16 (W^T) ----------------
__global__ __launch_bounds__(256) void wtrans_kernel(
    const float* __restrict__ Wq, const float* __restrict__ Wk,
    const float* __restrict__ Wv, const float* __restrict__ Wo,
    bf16* __restrict__ WTqkv, bf16* __restrict__ WoT) {
  __shared__ float tile[32][33];
  const int mat = blockIdx.z;
  const float* W = (mat == 0) ? Wq : (mat == 1) ? Wk : (mat == 2) ? Wv : Wo;
  bf16* WT = (mat < 3) ? (WTqkv + (size_t)mat * HIDDEN * HIDDEN) : WoT;
  const int tx = threadIdx.x & 31, ty = threadIdx.x >> 5;
  const int n0 = blockIdx.x * 32, k0 = blockIdx.y * 32;
  #pragma unroll
  for (int i = 0; i < 32; i += 8)
    tile[ty + i][tx] = W[(size_t)(k0 + ty + i) * HIDDEN + n0 + tx];
  __syncthreads();
  #pragma unroll
  for (int i = 0; i < 32; i += 8)
    WT[(size_t)(n0 + ty + i) * HIDDEN + k0 + tx] = __float2bfloat16(tile[tx][ty + i]);
}

// ---------------- GEMM: C[M,N] = A[M,K] * Bt[N,K]^T  (m97-style) ----------------
template <int EPI>
__global__ __launch_bounds__(256) void gemm_kernel(
    const bf16* __restrict__ A, const bf16* __restrict__ Bt, int Ksz,
    const float* __restrict__ bias0, const float* __restrict__ bias1,
    const float* __restrict__ bias2, const float* __restrict__ resid,
    bf16* __restrict__ q_out, bf16* __restrict__ k_out, bf16* __restrict__ v_out,
    float* __restrict__ f_out) {
  __shared__ bf16 As[128 * 32];
  __shared__ bf16 Bs[128 * 32];
  const int t = threadIdx.x;
  const int wave = t >> 6, lane = t & 63;
  const int wr = wave >> 1, wc = wave & 1;
  const int m0 = blockIdx.y * 128, n0 = blockIdx.x * 128;
  const int lr = lane & 15, lk = (lane >> 4) * 8;
  const f32x4 zero = {0.f, 0.f, 0.f, 0.f};
  f32x4 acc[4][4];
  #pragma unroll
  for (int i = 0; i < 4; ++i)
    #pragma unroll
    for (int j = 0; j < 4; ++j) acc[i][j] = zero;

  const int ar = t >> 2;
  const int ac = (t & 3) * 8;
  const bf16* Ag = A + (size_t)(m0 + ar) * Ksz + ac;
  const bf16* Bg = Bt + (size_t)(n0 + ar) * Ksz + ac;

  for (int k0 = 0; k0 < Ksz; k0 += 32) {
    if (k0) __syncthreads();
    gload_lds16(Ag + k0,                     &As[t * 8]);
    gload_lds16(Ag + (size_t)64 * Ksz + k0,  &As[2048 + t * 8]);
    gload_lds16(Bg + k0,                     &Bs[t * 8]);
    gload_lds16(Bg + (size_t)64 * Ksz + k0,  &Bs[2048 + t * 8]);
    __syncthreads();
    bf16x8 af[4], bfr[4];
    #pragma unroll
    for (int i = 0; i < 4; ++i)
      af[i] = *reinterpret_cast<const bf16x8*>(&As[(wr * 64 + i * 16 + lr) * 32 + lk]);
    #pragma unroll
    for (int i = 0; i < 4; ++i)
      bfr[i] = *reinterpret_cast<const bf16x8*>(&Bs[(wc * 64 + i * 16 + lr) * 32 + lk]);
    #pragma unroll
    for (int i = 0; i < 4; ++i)
      #pragma unroll
      for (int j = 0; j < 4; ++j)
        acc[i][j] = MFMA16(af[i], bfr[j], acc[i][j]);
  }

  const int rb = (lane >> 4) * 4;
  if (EPI == 0) {
    #pragma unroll
    for (int nf = 0; nf < 4; ++nf) {
      const int cg = n0 + wc * 64 + nf * 16 + lr;
      const int which = cg >> 10;
      const int hid = cg & 1023;
      const int head = hid >> 6, d = hid & 63;
      const float bias = (which == 0 ? bias0 : which == 1 ? bias1 : bias2)[hid];
      #pragma unroll
      for (int mf = 0; mf < 4; ++mf) {
        #pragma unroll
        for (int j = 0; j < 4; ++j) {
          const int rg = m0 + wr * 64 + mf * 16 + rb + j;
          const int b_ = rg >> 11, l_ = rg & 2047;
          const float val = acc[mf][nf][j] + bias;
          const size_t off = ((size_t)(b_ * NHEADS + head) * SEQ + l_) * HEADD + d;
          if (which == 2)       v_out[off] = __float2bfloat16(val);
          else if (which == 1)  k_out[off] = __float2bfloat16(val);
          else                  q_out[off] = __float2bfloat16(val * QK_SCALE);
        }
      }
    }
  } else {
    #pragma unroll
    for (int nf = 0; nf < 4; ++nf) {
      const int cg = n0 + wc * 64 + nf * 16 + lr;
      const float bias = bias0[cg];
      #pragma unroll
      for (int mf = 0; mf < 4; ++mf) {
        #pragma unroll
        for (int j = 0; j < 4; ++j) {
          const int rg = m0 + wr * 64 + mf * 16 + rb + j;
          const size_t off = (size_t)rg * HIDDEN + cg;
          f_out[off] = acc[mf][nf][j] + bias + resid[off];
        }
      }
    }
  }
}

// ---------------- V transpose [B,H,L,D] -> [B,H,D,L] ----------------
__global__ __launch_bounds__(256) void vtrans_kernel(
    const unsigned short* __restrict__ V, unsigned short* __restrict__ Vt) {
  __shared__ unsigned short tile[64][72];
  const int bh = blockIdx.y;
  const int l0 = blockIdx.x * 64;
  const int t = threadIdx.x;
  const unsigned short* Vs = V + ((size_t)bh * SEQ + l0) * HEADD;
  #pragma unroll
  for (int p = 0; p < 4; ++p) {
    const int idx = p * 256 + t;
    const int r = idx >> 4;
    const int c = (idx & 15) * 4;
    ushort4 v4 = *reinterpret_cast<const ushort4*>(&Vs[r * HEADD + c]);
    tile[r][c] = v4.x; tile[r][c + 1] = v4.y; tile[r][c + 2] = v4.z; tile[r][c + 3] = v4.w;
  }
  __syncthreads();
  unsigned short* Vd = Vt + (size_t)bh * HEADD * SEQ + l0;
  #pragma unroll
  for (int p = 0; p < 4; ++p) {
    const int idx = p * 256 + t;
    const int d = idx >> 4;
    const int c = (idx & 15) * 4;
    ushort4 o4 = make_ushort4(tile[c][d], tile[c + 1][d], tile[c + 2][d], tile[c + 3][d]);
    *reinterpret_cast<ushort4*>(&Vd[(size_t)d * SEQ + c]) = o4;
  }
}

// ---------------- Causal flash attention (v4: LDS-staged K/V, dbuf, counted vmcnt) ----
// 256 thr = 4 waves, each owns 32 q-rows (block = 128 q-rows). All waves share
// K/V tiles staged cooperatively into LDS via global_load_lds (linear dest +
// inverse-swizzled global source; reads apply byte ^= ((row&7)<<4)).
// Double-buffered; per-wave s_waitcnt vmcnt(4) (never full drain) + raw s_barrier.
// Swapped QK^T (32x32): lane ql holds P-row ql at 32 of 64 kv; in-lane softmax
// with defer-max; P roundtrip via wave-private swizzled LDS.
__global__ __launch_bounds__(256, 3) void attn_kernel(
    const bf16* __restrict__ Q, const bf16* __restrict__ K,
    const bf16* __restrict__ Vt, bf16* __restrict__ O) {
  __shared__ __align__(16) char KVlds[2][16384];     // per buf: K tile 8KB | V tile 8KB
  __shared__ unsigned long long Plds[4][32 * 16];    // per-wave 4KB P roundtrip
  const int wave = threadIdx.x >> 6, lane = threadIdx.x & 63;
  const int ql = lane & 31, hi = lane >> 5;
  const int bh = blockIdx.y;
  const int s = 15 - (int)blockIdx.x;                // LPT
  const int q0 = s * 128 + wave * 32;
  const int NT = 2 * s + 2;                          // kv tiles for this block
  const bf16* Qh = Q + (size_t)bh * SEQ * HEADD;
  const char* Kg = (const char*)(K + (size_t)bh * SEQ * HEADD);
  const char* Vg = (const char*)(Vt + (size_t)bh * HEADD * SEQ);
  unsigned long long* Pw = &Plds[wave][0];

  // stage tile -> KVlds[buf]: dest linear (G*16), source inverse-swizzled.
  // granule g (of 512 per half): row=g>>3, slot=g&7, logical col-slice cs=slot^(row&7).
  auto stage = [&](int buf, int tile) {
    const int kv0t = tile * 64;
    #pragma unroll
    for (int i = 0; i < 4; ++i) {
      const int G = i * 256 + (int)threadIdx.x;      // 0..1023
      const int g = G & 511;
      const int row = g >> 3;
      const int cs = (g & 7) ^ (row & 7);
      const char* src = (G < 512)
          ? Kg + ((size_t)(kv0t + row) * 128 + cs * 16)
          : Vg + ((size_t)row * (SEQ * 2) + (size_t)kv0t * 2 + cs * 16);
      gload_lds16(src, &KVlds[buf][0] + (size_t)G * 16);
    }
  };

  // Q fragments (B-operand): lane holds Q[q0+ql][hi*8 + 16j ..]
  const bf16* Qr = &Qh[(size_t)(q0 + ql) * HEADD + hi * 8];
  const bf16x8 qf0 = *reinterpret_cast<const bf16x8*>(Qr);
  const bf16x8 qf1 = *reinterpret_cast<const bf16x8*>(Qr + 16);
  const bf16x8 qf2 = *reinterpret_cast<const bf16x8*>(Qr + 32);
  const bf16x8 qf3 = *reinterpret_cast<const bf16x8*>(Qr + 48);

  const f32x16 z16 = {0.f,0.f,0.f,0.f,0.f,0.f,0.f,0.f,0.f,0.f,0.f,0.f,0.f,0.f,0.f,0.f};
  f32x16 o0 = z16, o1 = z16;
  float mrun = 0.f, lsum = 0.f;
  const int rq = q0 + ql;
  const int swz = ql & 15;
  const int rsw = ql & 7;

  stage(0, 0);
  for (int t = 0; t < NT; ++t) {
    const int cur = t & 1;
    if (t + 1 < NT) {
      stage(cur ^ 1, t + 1);
      asm volatile("s_waitcnt vmcnt(4)" ::: "memory");   // tile t's 4 loads done; t+1 in flight
    } else {
      asm volatile("s_waitcnt vmcnt(0)" ::: "memory");
    }
    __builtin_amdgcn_s_barrier();
    asm volatile("" ::: "memory");
    const int kv0 = t * 64;
    if (kv0 <= q0 + 31) {                                // skip fully-masked tiles
      const char* Kb = &KVlds[cur][0];
      const char* Vb = &KVlds[cur][8192];
      // --- QK^T (swapped): A = K rows (kv), B = Q cols (q) ---
      f32x16 s0 = z16, s1 = z16;
      __builtin_amdgcn_s_setprio(1);
      {
        bf16x8 kf;
        kf = *(const bf16x8*)(Kb + ql * 128        + (((0 + hi) ^ rsw) << 4)); s0 = MFMA32(kf, qf0, s0);
        kf = *(const bf16x8*)(Kb + ql * 128        + (((2 + hi) ^ rsw) << 4)); s0 = MFMA32(kf, qf1, s0);
        kf = *(const bf16x8*)(Kb + ql * 128        + (((4 + hi) ^ rsw) << 4)); s0 = MFMA32(kf, qf2, s0);
        kf = *(const bf16x8*)(Kb + ql * 128        + (((6 + hi) ^ rsw) << 4)); s0 = MFMA32(kf, qf3, s0);
        kf = *(const bf16x8*)(Kb + (ql + 32) * 128 + (((0 + hi) ^ rsw) << 4)); s1 = MFMA32(kf, qf0, s1);
        kf = *(const bf16x8*)(Kb + (ql + 32) * 128 + (((2 + hi) ^ rsw) << 4)); s1 = MFMA32(kf, qf1, s1);
        kf = *(const bf16x8*)(Kb + (ql + 32) * 128 + (((4 + hi) ^ rsw) << 4)); s1 = MFMA32(kf, qf2, s1);
        kf = *(const bf16x8*)(Kb + (ql + 32) * 128 + (((6 + hi) ^ rsw) << 4)); s1 = MFMA32(kf, qf3, s1);
      }
      __builtin_amdgcn_s_setprio(0);
      // --- causal mask (diagonal tile only) ---
      if (kv0 + 63 > rq) {
        #pragma unroll
        for (int r = 0; r < 16; ++r) {
          const int kvg = kv0 + (r & 3) + 8 * (r >> 2) + 4 * hi;
          if (kvg > rq)      s0[r] = -1e30f;
          if (kvg + 32 > rq) s1[r] = -1e30f;
        }
      }
      // --- in-lane rowmax tree ---
      float tm[16];
      #pragma unroll
      for (int r = 0; r < 16; ++r) tm[r] = fmaxf(s0[r], s1[r]);
      #pragma unroll
      for (int st = 8; st >= 1; st >>= 1)
        #pragma unroll
        for (int r = 0; r < st; ++r) tm[r] = fmaxf(tm[r], tm[r + st]);
      const float pmax = tm[0];
      // --- defer-max rescale (rare) ---
      if (!__all(pmax - mrun <= 8.f)) {
        const float fullmax = fmaxf(pmax, __shfl_xor(pmax, 32));
        const float mnew = fmaxf(mrun, fullmax);
        const float al = __expf(mrun - mnew);
        float* Pa = (float*)Pw;
        Pa[ql] = al;
        asm volatile("s_waitcnt lgkmcnt(0)" ::: "memory");
        __builtin_amdgcn_sched_barrier(0);
        #pragma unroll
        for (int r = 0; r < 16; ++r) {
          const float ar = Pa[(r & 3) + 8 * (r >> 2) + 4 * hi];
          o0[r] *= ar; o1[r] *= ar;
        }
        lsum *= al;
        mrun = mnew;
        __builtin_amdgcn_sched_barrier(0);
      }
      // --- exp + rowsum ---
      #pragma unroll
      for (int r = 0; r < 16; ++r) {
        s0[r] = __expf(s0[r] - mrun);
        s1[r] = __expf(s1[r] - mrun);
      }
      #pragma unroll
      for (int r = 0; r < 16; ++r) tm[r] = s0[r] + s1[r];
      #pragma unroll
      for (int st = 8; st >= 1; st >>= 1)
        #pragma unroll
        for (int r = 0; r < st; ++r) tm[r] += tm[r + st];
      lsum += tm[0];
      // --- pack P -> LDS (b64, XOR-swizzled 8B granules) ---
      #pragma unroll
      for (int i = 0; i < 8; ++i) {
        const int g = 2 * (i & 3) + hi + 8 * (i >> 2);
        unsigned long long w;
        if (i < 4) w = pack4bf(s0[4*i],     s0[4*i+1],     s0[4*i+2],     s0[4*i+3]);
        else       w = pack4bf(s1[4*(i-4)], s1[4*(i-4)+1], s1[4*(i-4)+2], s1[4*(i-4)+3]);
        Pw[ql * 16 + (g ^ swz)] = w;
      }
      asm volatile("s_waitcnt lgkmcnt(0)" ::: "memory");
      __builtin_amdgcn_sched_barrier(0);
      // --- PV: A = P[q][kv-slice], B = V[d][kv] from LDS ---
      __builtin_amdgcn_s_setprio(1);
      #pragma unroll
      for (int ks = 0; ks < 4; ++ks) {
        const int ga = (4 * ks + 2 * hi) ^ swz;
        const int gb = (4 * ks + 2 * hi + 1) ^ swz;
        union { unsigned long long u[2]; bf16x8 v; } uu;
        uu.u[0] = Pw[ql * 16 + ga];
        uu.u[1] = Pw[ql * 16 + gb];
        const int voff = ((2 * ks + hi) ^ rsw) << 4;
        const bf16x8 v0 = *(const bf16x8*)(Vb + ql * 128 + voff);
        const bf16x8 v1 = *(const bf16x8*)(Vb + (ql + 32) * 128 + voff);
        o0 = MFMA32(uu.v, v0, o0);
        o1 = MFMA32(uu.v, v1, o1);
      }
      __builtin_amdgcn_s_setprio(0);
    }
    asm volatile("" ::: "memory");
    __builtin_amdgcn_s_barrier();
  }

  // --- epilogue ---
  const float ltot = lsum + __shfl_xor(lsum, 32);
  float* Pb = (float*)Pw;
  Pb[ql] = 1.0f / ltot;
  asm volatile("s_waitcnt lgkmcnt(0)" ::: "memory");
  __builtin_amdgcn_sched_barrier(0);
  const int b_ = bh >> 4, h_ = bh & 15;
  #pragma unroll
  for (int r = 0; r < 16; ++r) {
    const int row = (r & 3) + 8 * (r >> 2) + 4 * hi;
    const float iv = Pb[row];
    bf16* dst = &O[((size_t)(b_ * SEQ + q0 + row)) * HIDDEN + h_ * HEADD + ql];
    dst[0]  = __float2bfloat16(o0[r] * iv);
    dst[32] = __float2bfloat16(o1[r] * iv);
  }
}

// ---------------- launch ----------------
extern "C" void kernel_launch(void* const* d_in, const int* in_sizes, int n_in,
                              void* d_out, int out_size, void* d_ws, size_t ws_size,
                              hipStream_t stream) {
  const float* x     = (const float*)d_in[0];
  const float* Wq    = (const float*)d_in[2];
  const float* bq    = (const float*)d_in[3];
  const float* Wk    = (const float*)d_in[4];
  const float* bk    = (const float*)d_in[5];
  const float* Wv    = (const float*)d_in[6];
  const float* bv    = (const float*)d_in[7];
  const float* Wo    = (const float*)d_in[8];
  const float* bo    = (const float*)d_in[9];
  const float* gamma = (const float*)d_in[10];
  const float* beta  = (const float*)d_in[11];

  char* ws = (char*)d_ws;
  const size_t MB = (size_t)1 << 20;
  bf16* h     = (bf16*)(ws + 0 * MB);
  bf16* Qb    = (bf16*)(ws + 16 * MB);
  bf16* Kb    = (bf16*)(ws + 32 * MB);
  bf16* Vtmp  = (bf16*)(ws + 48 * MB);
  bf16* Vt    = (bf16*)(ws + 64 * MB);
  bf16* WTqkv = (bf16*)(ws + 80 * MB);
  bf16* WoT   = (bf16*)(ws + 86 * MB);
  bf16* Ob    = h;

  ln_cast_kernel<<<MROWS, 256, 0, stream>>>(x, gamma, beta, h);
  wtrans_kernel<<<dim3(32, 32, 4), 256, 0, stream>>>(Wq, Wk, Wv, Wo, WTqkv, WoT);
  gemm_kernel<0><<<dim3(24, 64), 256, 0, stream>>>(
      h, WTqkv, HIDDEN, bq, bk, bv, nullptr, Qb, Kb, Vtmp, nullptr);
  vtrans_kernel<<<dim3(SEQ / 64, BATCH * NHEADS), 256, 0, stream>>>(
      (const unsigned short*)Vtmp, (unsigned short*)Vt);
  attn_kernel<<<dim3(16, BATCH * NHEADS), 256, 0, stream>>>(Qb, Kb, Vt, Ob);
  gemm_kernel<1><<<dim3(8, 64), 256, 0, stream>>>(
      Ob, WoT, HIDDEN, bo, nullptr, nullptr, x, nullptr, nullptr, nullptr, (float*)d_out);
}